// Round 1
// baseline (2085.678 us; speedup 1.0000x reference)
//
#include <hip/hip_runtime.h>
#include <cstddef>

// SSA (spiking self-attention) forward, fp32 baseline.
// B=32, C=512, N=1024. LIF forward == Heaviside, so q/k/v/attn/out are {0,1}.

#define CC 512
#define BB 32
#define NN 1024
#define BNC 32768  // B*N, BatchNorm reduction count per channel

// ---------------- GEMM NN: Y[b] = W (CCxCC) * X[b] (CCxNN) (+ bias) -------------
template <bool WITH_BIAS>
__global__ __launch_bounds__(256) void gemm_nn_k(const float* __restrict__ W,
                                                 const float* __restrict__ X,
                                                 const float* __restrict__ bias,
                                                 float* __restrict__ Y) {
  __shared__ float As[16][65];  // As[k][m], padded (+1) so transpose-store is conflict-free
  __shared__ float Bs[16][64];  // Bs[k][n]
  const int b = blockIdx.z;
  const float* Xb = X + (size_t)b * CC * NN;
  float* Yb = Y + (size_t)b * CC * NN;
  const int m0 = blockIdx.y * 64, n0 = blockIdx.x * 64;
  const int tid = threadIdx.y * 16 + threadIdx.x;
  float acc[4][4] = {};
  for (int k0 = 0; k0 < CC; k0 += 16) {
#pragma unroll
    for (int i = 0; i < 4; i++) {  // W tile: 64 m x 16 k, k fastest (coalesced 64B runs)
      int e = tid + i * 256;
      int m = e >> 4, k = e & 15;
      As[k][m] = W[(size_t)(m0 + m) * CC + (k0 + k)];
    }
#pragma unroll
    for (int i = 0; i < 4; i++) {  // X tile: 16 k x 64 n, n fastest (fully coalesced)
      int e = tid + i * 256;
      int k = e >> 6, n = e & 63;
      Bs[k][n] = Xb[(size_t)(k0 + k) * NN + (n0 + n)];
    }
    __syncthreads();
#pragma unroll
    for (int kk = 0; kk < 16; kk++) {
      float a[4], bb[4];
#pragma unroll
      for (int i = 0; i < 4; i++) a[i] = As[kk][threadIdx.y * 4 + i];
#pragma unroll
      for (int j = 0; j < 4; j++) bb[j] = Bs[kk][threadIdx.x * 4 + j];
#pragma unroll
      for (int i = 0; i < 4; i++)
#pragma unroll
        for (int j = 0; j < 4; j++) acc[i][j] += a[i] * bb[j];
    }
    __syncthreads();
  }
#pragma unroll
  for (int i = 0; i < 4; i++) {
    int m = m0 + threadIdx.y * 4 + i;
    float bi = WITH_BIAS ? bias[m] : 0.f;
#pragma unroll
    for (int j = 0; j < 4; j++) {
      int n = n0 + threadIdx.x * 4 + j;
      Yb[(size_t)m * NN + n] = acc[i][j] + bi;
    }
  }
}

// ---------------- GEMM NT: kv[b] (CCxCC) = Ks[b] (CCxNN) * Vs[b]^T ---------------
__global__ __launch_bounds__(256) void gemm_nt_kv(const float* __restrict__ Ks,
                                                  const float* __restrict__ Vs,
                                                  float* __restrict__ KV) {
  __shared__ float As[16][65];  // As[k][m=c]
  __shared__ float Bs[16][65];  // Bs[k][n=d]
  const int b = blockIdx.z;
  const float* Ab = Ks + (size_t)b * CC * NN;
  const float* Bb_ = Vs + (size_t)b * CC * NN;
  float* KVb = KV + (size_t)b * CC * CC;
  const int m0 = blockIdx.y * 64, n0 = blockIdx.x * 64;
  const int tid = threadIdx.y * 16 + threadIdx.x;
  float acc[4][4] = {};
  for (int k0 = 0; k0 < NN; k0 += 16) {
#pragma unroll
    for (int i = 0; i < 4; i++) {
      int e = tid + i * 256;
      int m = e >> 4, k = e & 15;
      As[k][m] = Ab[(size_t)(m0 + m) * NN + (k0 + k)];
    }
#pragma unroll
    for (int i = 0; i < 4; i++) {
      int e = tid + i * 256;
      int n = e >> 4, k = e & 15;
      Bs[k][n] = Bb_[(size_t)(n0 + n) * NN + (k0 + k)];
    }
    __syncthreads();
#pragma unroll
    for (int kk = 0; kk < 16; kk++) {
      float a[4], bb[4];
#pragma unroll
      for (int i = 0; i < 4; i++) a[i] = As[kk][threadIdx.y * 4 + i];
#pragma unroll
      for (int j = 0; j < 4; j++) bb[j] = Bs[kk][threadIdx.x * 4 + j];
#pragma unroll
      for (int i = 0; i < 4; i++)
#pragma unroll
        for (int j = 0; j < 4; j++) acc[i][j] += a[i] * bb[j];
    }
    __syncthreads();
  }
#pragma unroll
  for (int i = 0; i < 4; i++) {
    int m = m0 + threadIdx.y * 4 + i;
#pragma unroll
    for (int j = 0; j < 4; j++) {
      int n = n0 + threadIdx.x * 4 + j;
      KVb[(size_t)m * CC + n] = acc[i][j];
    }
  }
}

// ------- GEMM TN + spike: attn[b,d,n] = H( 0.125*sum_c q[b,c,n]*kv[b,c,d] /1.1 - 0.5 )
__global__ __launch_bounds__(256) void gemm_tn_attn(const float* __restrict__ KV,
                                                    const float* __restrict__ Qs,
                                                    float* __restrict__ Attn) {
  __shared__ float As[16][64];  // As[k=c][m=d] — loaded directly, no transpose
  __shared__ float Bs[16][64];  // Bs[k=c][n]
  const int b = blockIdx.z;
  const float* KVb = KV + (size_t)b * CC * CC;
  const float* Qb = Qs + (size_t)b * CC * NN;
  float* Ob = Attn + (size_t)b * CC * NN;
  const int m0 = blockIdx.y * 64, n0 = blockIdx.x * 64;
  const int tid = threadIdx.y * 16 + threadIdx.x;
  float acc[4][4] = {};
  for (int k0 = 0; k0 < CC; k0 += 16) {
#pragma unroll
    for (int i = 0; i < 4; i++) {  // KV tile: rows k=c, cols m=d (contiguous in d)
      int e = tid + i * 256;
      int k = e >> 6, m = e & 63;
      As[k][m] = KVb[(size_t)(k0 + k) * CC + (m0 + m)];
    }
#pragma unroll
    for (int i = 0; i < 4; i++) {
      int e = tid + i * 256;
      int k = e >> 6, n = e & 63;
      Bs[k][n] = Qb[(size_t)(k0 + k) * NN + (n0 + n)];
    }
    __syncthreads();
#pragma unroll
    for (int kk = 0; kk < 16; kk++) {
      float a[4], bb[4];
#pragma unroll
      for (int i = 0; i < 4; i++) a[i] = As[kk][threadIdx.y * 4 + i];
#pragma unroll
      for (int j = 0; j < 4; j++) bb[j] = Bs[kk][threadIdx.x * 4 + j];
#pragma unroll
      for (int i = 0; i < 4; i++)
#pragma unroll
        for (int j = 0; j < 4; j++) acc[i][j] += a[i] * bb[j];
    }
    __syncthreads();
  }
#pragma unroll
  for (int i = 0; i < 4; i++) {
    int m = m0 + threadIdx.y * 4 + i;
#pragma unroll
    for (int j = 0; j < 4; j++) {
      int n = n0 + threadIdx.x * 4 + j;
      float u = (acc[i][j] * 0.125f) / 1.1f - 0.5f;  // lif(attn, 0.5)
      Ob[(size_t)m * NN + n] = (u >= 0.f) ? 1.f : 0.f;
    }
  }
}

// ---------------- BN stats (training): per-channel mean & rsqrt(var+eps) --------
__global__ __launch_bounds__(256) void bn_stats_k(const float* __restrict__ Y,
                                                  float* __restrict__ stat) {
  const int c = blockIdx.x;
  const int tid = threadIdx.x;
  __shared__ float red[4];
  __shared__ float meansh;
  float s = 0.f;
  for (int i = tid; i < BNC; i += 256) {
    int b = i >> 10, n = i & 1023;
    s += Y[(size_t)b * CC * NN + (size_t)c * NN + n];
  }
#pragma unroll
  for (int off = 32; off > 0; off >>= 1) s += __shfl_down(s, off, 64);
  int wave = tid >> 6, lane = tid & 63;
  if (lane == 0) red[wave] = s;
  __syncthreads();
  if (tid == 0) meansh = (red[0] + red[1] + red[2] + red[3]) / 32768.f;
  __syncthreads();
  float mean = meansh;
  float s2 = 0.f;
  for (int i = tid; i < BNC; i += 256) {  // two-pass variance (faithful, no cancellation)
    int b = i >> 10, n = i & 1023;
    float d = Y[(size_t)b * CC * NN + (size_t)c * NN + n] - mean;
    s2 += d * d;
  }
#pragma unroll
  for (int off = 32; off > 0; off >>= 1) s2 += __shfl_down(s2, off, 64);
  if (lane == 0) red[wave] = s2;
  __syncthreads();
  if (tid == 0) {
    float var = (red[0] + red[1] + red[2] + red[3]) / 32768.f;
    stat[c] = mean;
    stat[CC + c] = 1.0f / sqrtf(var + 1e-5f);
  }
}

// ---------------- elementwise BN-apply + LIF spike ------------------------------
__global__ __launch_bounds__(256) void spike_k(const float* __restrict__ Yin,
                                               float* __restrict__ Yout,
                                               const float* __restrict__ stat,
                                               const float* __restrict__ gamma,
                                               const float* __restrict__ beta,
                                               float vth) {
  size_t i = ((size_t)blockIdx.x * 256 + threadIdx.x) * 4;
  int c = (int)((i >> 10) & 511);
  float mean = stat[c], rs = stat[CC + c], g = gamma[c], bt = beta[c];
  float4 y = *(const float4*)(Yin + i);
  float4 o;
  float v;
  v = g * (y.x - mean) * rs + bt; o.x = (v / 1.1f - vth >= 0.f) ? 1.f : 0.f;
  v = g * (y.y - mean) * rs + bt; o.y = (v / 1.1f - vth >= 0.f) ? 1.f : 0.f;
  v = g * (y.z - mean) * rs + bt; o.z = (v / 1.1f - vth >= 0.f) ? 1.f : 0.f;
  v = g * (y.w - mean) * rs + bt; o.w = (v / 1.1f - vth >= 0.f) ? 1.f : 0.f;
  *(float4*)(Yout + i) = o;
}

extern "C" void kernel_launch(void* const* d_in, const int* in_sizes, int n_in,
                              void* d_out, int out_size, void* d_ws, size_t ws_size,
                              hipStream_t stream) {
  // setup_inputs() dict order:
  const float* x          = (const float*)d_in[0];
  const float* q_w        = (const float*)d_in[1];
  const float* q_gamma    = (const float*)d_in[2];
  const float* q_beta     = (const float*)d_in[3];
  const float* k_w        = (const float*)d_in[4];
  const float* k_gamma    = (const float*)d_in[5];
  const float* k_beta     = (const float*)d_in[6];
  const float* v_w        = (const float*)d_in[7];
  const float* v_gamma    = (const float*)d_in[8];
  const float* v_beta     = (const float*)d_in[9];
  const float* proj_w     = (const float*)d_in[10];
  const float* proj_gamma = (const float*)d_in[11];
  const float* proj_beta  = (const float*)d_in[12];
  const float* proj_b     = (const float*)d_in[13];

  float* ws = (float*)d_ws;
  const size_t T = (size_t)BB * CC * NN;  // 16,777,216
  float* yq = ws;
  float* yk = ws + T;
  float* yv = ws + 2 * T;
  float* kv = ws + 3 * T;                        // [B,C,C] = 8,388,608 floats
  float* st = ws + 3 * T + (size_t)BB * CC * CC; // stats: 4 x 1024 floats
  float* stq = st, *stk = st + 1024, *stv = st + 2048, *sto = st + 3072;
  float* attn = yv;  // v spikes consumed by kv kernel before attn is written
  float* outb = yk;  // k spikes consumed by kv kernel before proj out is written
  float* dout = (float*)d_out;

  dim3 blk(16, 16);
  dim3 g_nn(NN / 64, CC / 64, BB);  // (16,8,32)
  dim3 g_nt(CC / 64, CC / 64, BB);  // (8,8,32)

  // q/k/v pointwise convs
  gemm_nn_k<false><<<g_nn, blk, 0, stream>>>(q_w, x, nullptr, yq);
  gemm_nn_k<false><<<g_nn, blk, 0, stream>>>(k_w, x, nullptr, yk);
  gemm_nn_k<false><<<g_nn, blk, 0, stream>>>(v_w, x, nullptr, yv);
  // BN stats
  bn_stats_k<<<CC, 256, 0, stream>>>(yq, stq);
  bn_stats_k<<<CC, 256, 0, stream>>>(yk, stk);
  bn_stats_k<<<CC, 256, 0, stream>>>(yv, stv);
  // BN-apply + LIF (in place)
  spike_k<<<16384, 256, 0, stream>>>(yq, yq, stq, q_gamma, q_beta, 1.0f);
  spike_k<<<16384, 256, 0, stream>>>(yk, yk, stk, k_gamma, k_beta, 1.0f);
  spike_k<<<16384, 256, 0, stream>>>(yv, yv, stv, v_gamma, v_beta, 1.0f);
  // kv = k . v^T  (per batch)
  gemm_nt_kv<<<g_nt, blk, 0, stream>>>(yk, yv, kv);
  // attn = spike(kv^T . q * 0.125, vth=0.5)
  gemm_tn_attn<<<g_nn, blk, 0, stream>>>(kv, yq, attn);
  // proj conv + bias
  gemm_nn_k<true><<<g_nn, blk, 0, stream>>>(proj_w, attn, proj_b, outb);
  // final BN + LIF -> d_out
  bn_stats_k<<<CC, 256, 0, stream>>>(outb, sto);
  spike_k<<<16384, 256, 0, stream>>>(outb, dout, sto, proj_gamma, proj_beta, 1.0f);
}

// Round 2
// 536.669 us; speedup vs baseline: 3.8863x; 3.8863x over previous
//
#include <hip/hip_runtime.h>
#include <cstddef>

// SSA forward, bf16-MFMA version.
// All 5 GEMMs are NT GEMMs on row-major [rows][K] operands (K contiguous):
//   conv q/k/v : out[o][n] = sum_c W[o][c] * xT[n][c]         (A=W, B=xT)
//   kvT        : kvT[d][c] = sum_n v[d][n] * k[c][n]          (A=v_s, B=k_s)
//   attnT      : attnT[n][d] = sum_c qT[n][c] * kvT[d][c]     (A=qT_s, B=kvT)
//   proj       : out[o][n] = sum_d Wp[o][d] * attnT[n][d]     (A=Wp, B=attnT)
// Spikes are {0,1} -> bf16 MFMA exact; attn margin S~1300 vs threshold 4.4.

#define CC 512
#define BB 32
#define NN 1024

typedef __attribute__((ext_vector_type(8))) short v8s;
typedef __attribute__((ext_vector_type(4))) float v4f;

__device__ __forceinline__ ushort f2bf(float f) {
  unsigned u = __float_as_uint(f);
  unsigned r = (u + 0x7FFFu + ((u >> 16) & 1u)) >> 16;
  return (ushort)r;
}
__device__ __forceinline__ float bf2f(ushort h) {
  return __uint_as_float((unsigned)h << 16);
}

__device__ __forceinline__ void gload16(const void* g, void* l) {
  __builtin_amdgcn_global_load_lds(
      (const __attribute__((address_space(1))) unsigned int*)g,
      (__attribute__((address_space(3))) unsigned int*)l, 16, 0, 0);
}

// ---------------- batched NT GEMM, 128x128 tile, BK=32, bf16 MFMA ----------------
// C[i][j] = sum_k A[i][k]*B[j][k];  A:[M][K], B:[Ngemm][K], C:[M][Ngemm] row-major.
// EPI: 0 = store bf16(acc); 1 = attn spike; 2 = +bias[row] then bf16.
template <int EPI>
__global__ __launch_bounds__(256) void gemm_nt(const ushort* __restrict__ A,
                                               const ushort* __restrict__ B,
                                               ushort* __restrict__ C,
                                               const float* __restrict__ bias,
                                               int M, int N, int K,
                                               long sA, long sB, long sC) {
  __shared__ __align__(16) short lds[8192];  // A chunks [0,4096), B chunks [4096,8192)
  const int b = blockIdx.z;
  const ushort* Ab = A + (size_t)b * sA;
  const ushort* Bb = B + (size_t)b * sB;
  ushort* Cb = C + (size_t)b * sC;
  const int m0 = blockIdx.y * 128, n0 = blockIdx.x * 128;
  const int tid = threadIdx.x;
  const int wave = tid >> 6, lane = tid & 63;
  const int lrow = lane & 15, lquad = lane >> 4;

  v4f acc[4][4];
#pragma unroll
  for (int i = 0; i < 4; i++)
#pragma unroll
    for (int j = 0; j < 4; j++) acc[i][j] = (v4f)0.f;

  // Staging: 8 A-chunks + 8 B-chunks per K-step, each 16 rows x 32 k in exact
  // MFMA fragment order (lane L: row lrow, k = lquad*8..+7 -> LDS byte L*16).
  const int i0 = 2 * wave;
  const ushort* ga0 = Ab + (size_t)(m0 + 16 * i0 + lrow) * K + lquad * 8;
  const ushort* ga1 = ga0 + (size_t)16 * K;
  const ushort* gb0 = Bb + (size_t)(n0 + 16 * i0 + lrow) * K + lquad * 8;
  const ushort* gb1 = gb0 + (size_t)16 * K;
  short* la0 = lds + i0 * 512;
  short* la1 = la0 + 512;
  short* lb0 = lds + 4096 + i0 * 512;
  short* lb1 = lb0 + 512;
  const int wr = wave >> 1, wc = wave & 1;  // wave quadrant of the 128x128 tile
  const short* ra = lds + (4 * wr) * 512 + lane * 8;
  const short* rb = lds + 4096 + (4 * wc) * 512 + lane * 8;

  for (int k0 = 0; k0 < K; k0 += 32) {
    gload16(ga0, la0);
    gload16(ga1, la1);
    gload16(gb0, lb0);
    gload16(gb1, lb1);
    ga0 += 32; ga1 += 32; gb0 += 32; gb1 += 32;
    __syncthreads();
    v8s af[4], bf[4];
#pragma unroll
    for (int i = 0; i < 4; i++) af[i] = *(const v8s*)(ra + i * 512);
#pragma unroll
    for (int j = 0; j < 4; j++) bf[j] = *(const v8s*)(rb + j * 512);
#pragma unroll
    for (int i = 0; i < 4; i++)
#pragma unroll
      for (int j = 0; j < 4; j++)
        acc[i][j] = __builtin_amdgcn_mfma_f32_16x16x32_bf16(af[i], bf[j], acc[i][j], 0, 0, 0);
    __syncthreads();
  }

  // Epilogue. C/D layout: col = lane&15, row = lquad*4 + reg.
#pragma unroll
  for (int mi = 0; mi < 4; mi++) {
    const int row0 = m0 + 64 * wr + 16 * mi + lquad * 4;
#pragma unroll
    for (int ni = 0; ni < 4; ni++) {
      const int col = n0 + 64 * wc + 16 * ni + lrow;
      ushort* cp = Cb + (size_t)row0 * N + col;
#pragma unroll
      for (int r = 0; r < 4; r++) {
        float v = acc[mi][ni][r];
        ushort o;
        if (EPI == 1) {
          float u = (v * 0.125f) / 1.1f - 0.5f;  // lif(attn*SCALE, 0.5)
          o = (u >= 0.f) ? (ushort)0x3F80 : (ushort)0;
        } else {
          if (EPI == 2) v += bias[row0 + r];
          o = f2bf(v);
        }
        cp[(size_t)r * N] = o;
      }
    }
  }
}

// ---------------- BN (training stats) + LIF spike, [B,C,N] layout ---------------
// One block per channel. Single-pass sum/sumsq (var clamped >=0), then apply.
// FOUT: 0 -> bf16 {0,1}, 1 -> fp32 {0,1} (final output).
template <int FOUT>
__global__ __launch_bounds__(256) void bn_spike_k(const ushort* __restrict__ in,
                                                  void* __restrict__ outp,
                                                  const float* __restrict__ gamma,
                                                  const float* __restrict__ beta) {
  const int c = blockIdx.x;
  const int tid = threadIdx.x;
  float s = 0.f, s2 = 0.f;
  for (int i = tid; i < 4096; i += 256) {  // 32 batches x 128 chunks of 8 bf16
    const int bi = i >> 7, ch = i & 127;
    const uint4 u = *(const uint4*)(in + (size_t)bi * CC * NN + (size_t)c * NN + ch * 8);
    const unsigned w4[4] = {u.x, u.y, u.z, u.w};
#pragma unroll
    for (int t = 0; t < 4; t++) {
      float f0 = __uint_as_float(w4[t] << 16);
      float f1 = __uint_as_float(w4[t] & 0xFFFF0000u);
      s += f0 + f1;
      s2 += f0 * f0 + f1 * f1;
    }
  }
#pragma unroll
  for (int off = 32; off > 0; off >>= 1) {
    s += __shfl_down(s, off, 64);
    s2 += __shfl_down(s2, off, 64);
  }
  __shared__ float rs[4], rq[4];
  __shared__ float sh_mean, sh_rinv;
  const int w = tid >> 6, ln = tid & 63;
  if (ln == 0) { rs[w] = s; rq[w] = s2; }
  __syncthreads();
  if (tid == 0) {
    float S = rs[0] + rs[1] + rs[2] + rs[3];
    float Q = rq[0] + rq[1] + rq[2] + rq[3];
    float mean = S * (1.f / 32768.f);
    float var = fmaxf(Q * (1.f / 32768.f) - mean * mean, 0.f);
    sh_mean = mean;
    sh_rinv = 1.f / sqrtf(var + 1e-5f);
  }
  __syncthreads();
  const float mean = sh_mean, rinv = sh_rinv;
  const float g = gamma[c], bt = beta[c];
  for (int i = tid; i < 4096; i += 256) {
    const int bi = i >> 7, ch = i & 127;
    const size_t off = (size_t)bi * CC * NN + (size_t)c * NN + ch * 8;
    const uint4 u = *(const uint4*)(in + off);
    const unsigned w4[4] = {u.x, u.y, u.z, u.w};
    float f[8];
#pragma unroll
    for (int t = 0; t < 4; t++) {
      f[2 * t]     = __uint_as_float(w4[t] << 16);
      f[2 * t + 1] = __uint_as_float(w4[t] & 0xFFFF0000u);
    }
    if (FOUT) {
      float of[8];
#pragma unroll
      for (int t = 0; t < 8; t++) {
        float val = g * (f[t] - mean) * rinv + bt;
        of[t] = (val / 1.1f - 1.0f >= 0.f) ? 1.f : 0.f;
      }
      float* op = (float*)outp + off;
      *(float4*)op = make_float4(of[0], of[1], of[2], of[3]);
      *(float4*)(op + 4) = make_float4(of[4], of[5], of[6], of[7]);
    } else {
      unsigned o[4];
#pragma unroll
      for (int t = 0; t < 4; t++) {
        float v0 = g * (f[2 * t] - mean) * rinv + bt;
        float v1 = g * (f[2 * t + 1] - mean) * rinv + bt;
        unsigned lo = (v0 / 1.1f - 1.0f >= 0.f) ? 0x3F80u : 0u;
        unsigned hi = (v1 / 1.1f - 1.0f >= 0.f) ? 0x3F80u : 0u;
        o[t] = lo | (hi << 16);
      }
      uint4* op = (uint4*)((ushort*)outp + off);
      *op = make_uint4(o[0], o[1], o[2], o[3]);
    }
  }
}

// ---------------- tiled transpose [B,R,Ncol] -> [B,Ncol,R], out bf16 ------------
template <int FIN>  // 1: fp32 in, 0: bf16 in
__global__ __launch_bounds__(256) void transpose_k(const void* __restrict__ inp,
                                                   ushort* __restrict__ out,
                                                   int R, int Ncol) {
  __shared__ ushort tile[32][33];
  const int b = blockIdx.z;
  const int c0 = blockIdx.x * 32, r0 = blockIdx.y * 32;
  const int tx = threadIdx.x & 31, ty = threadIdx.x >> 5;
  const size_t base = (size_t)b * R * Ncol;
#pragma unroll
  for (int i = 0; i < 32; i += 8) {
    const size_t idx = base + (size_t)(r0 + ty + i) * Ncol + c0 + tx;
    ushort hv;
    if (FIN) hv = f2bf(((const float*)inp)[idx]);
    else hv = ((const ushort*)inp)[idx];
    tile[ty + i][tx] = hv;
  }
  __syncthreads();
#pragma unroll
  for (int i = 0; i < 32; i += 8) {
    out[base + (size_t)(c0 + ty + i) * R + r0 + tx] = tile[tx][ty + i];
  }
}

// ---------------- fp32 -> bf16 weight conversion (4 matrices) -------------------
__global__ __launch_bounds__(256) void wcvt_k(const float* __restrict__ w0, const float* __restrict__ w1,
                                              const float* __restrict__ w2, const float* __restrict__ w3,
                                              ushort* __restrict__ o0, ushort* __restrict__ o1,
                                              ushort* __restrict__ o2, ushort* __restrict__ o3) {
  const float* src;
  ushort* dst;
  switch (blockIdx.y) {
    case 0: src = w0; dst = o0; break;
    case 1: src = w1; dst = o1; break;
    case 2: src = w2; dst = o2; break;
    default: src = w3; dst = o3; break;
  }
  const int i = (blockIdx.x * 256 + threadIdx.x) * 4;
  float4 v = *(const float4*)(src + i);
  ushort4 o;
  o.x = f2bf(v.x); o.y = f2bf(v.y); o.z = f2bf(v.z); o.w = f2bf(v.w);
  *(ushort4*)(dst + i) = o;
}

extern "C" void kernel_launch(void* const* d_in, const int* in_sizes, int n_in,
                              void* d_out, int out_size, void* d_ws, size_t ws_size,
                              hipStream_t stream) {
  const float* x          = (const float*)d_in[0];
  const float* q_w        = (const float*)d_in[1];
  const float* q_gamma    = (const float*)d_in[2];
  const float* q_beta     = (const float*)d_in[3];
  const float* k_w        = (const float*)d_in[4];
  const float* k_gamma    = (const float*)d_in[5];
  const float* k_beta     = (const float*)d_in[6];
  const float* v_w        = (const float*)d_in[7];
  const float* v_gamma    = (const float*)d_in[8];
  const float* v_beta     = (const float*)d_in[9];
  const float* proj_w     = (const float*)d_in[10];
  const float* proj_gamma = (const float*)d_in[11];
  const float* proj_beta  = (const float*)d_in[12];
  const float* proj_b     = (const float*)d_in[13];

  ushort* ws = (ushort*)d_ws;
  const size_t T = (size_t)BB * CC * NN;   // 16,777,216 elems
  ushort* xT    = ws;                      // [B,N,C] bf16; reused as attnT
  ushort* qpre  = ws + T;                  // [B,C,N]; reused as outpre
  ushort* kpre  = ws + 2 * T;
  ushort* vpre  = ws + 3 * T;
  ushort* qTs   = ws + 4 * T;              // [B,N,C] q spikes
  ushort* kvT   = ws + 5 * T;              // [B,C,C] (=[d][c])
  ushort* wqb   = kvT + (size_t)BB * CC * CC;
  ushort* wkb   = wqb + CC * CC;
  ushort* wvb   = wkb + CC * CC;
  ushort* wpb   = wvb + CC * CC;
  ushort* attnT = xT;
  ushort* outpre = qpre;
  float* dout = (float*)d_out;

  const long TL = (long)CC * NN;      // per-batch [C][N] / [N][C] stride
  const long KVL = (long)CC * CC;

  // x [B,C,N] fp32 -> xT [B,N,C] bf16
  transpose_k<1><<<dim3(NN / 32, CC / 32, BB), 256, 0, stream>>>(x, xT, CC, NN);
  wcvt_k<<<dim3(CC * CC / 1024, 4), 256, 0, stream>>>(q_w, k_w, v_w, proj_w, wqb, wkb, wvb, wpb);

  // q/k/v convs: [o][n] = W * xT^T.  grid (N/128, M/128, B)
  dim3 gconv(NN / 128, CC / 128, BB);
  gemm_nt<0><<<gconv, 256, 0, stream>>>(wqb, xT, qpre, nullptr, CC, NN, CC, 0, TL, TL);
  gemm_nt<0><<<gconv, 256, 0, stream>>>(wkb, xT, kpre, nullptr, CC, NN, CC, 0, TL, TL);
  gemm_nt<0><<<gconv, 256, 0, stream>>>(wvb, xT, vpre, nullptr, CC, NN, CC, 0, TL, TL);

  bn_spike_k<0><<<CC, 256, 0, stream>>>(qpre, qpre, q_gamma, q_beta);
  bn_spike_k<0><<<CC, 256, 0, stream>>>(kpre, kpre, k_gamma, k_beta);
  bn_spike_k<0><<<CC, 256, 0, stream>>>(vpre, vpre, v_gamma, v_beta);

  // q spikes [B,C,N] -> qT [B,N,C]
  transpose_k<0><<<dim3(NN / 32, CC / 32, BB), 256, 0, stream>>>(qpre, qTs, CC, NN);

  // kvT[d][c] = sum_n v[d][n] k[c][n]
  gemm_nt<0><<<dim3(CC / 128, CC / 128, BB), 256, 0, stream>>>(vpre, kpre, kvT, nullptr, CC, CC, NN, TL, TL, KVL);
  // attnT[n][d] = spike( sum_c qT[n][c] kvT[d][c] * 0.125, vth=0.5 )
  gemm_nt<1><<<dim3(CC / 128, NN / 128, BB), 256, 0, stream>>>(qTs, kvT, attnT, nullptr, NN, CC, CC, TL, KVL, TL);
  // proj: out[o][n] = Wp * attnT^T + bias
  gemm_nt<2><<<gconv, 256, 0, stream>>>(wpb, attnT, outpre, proj_b, CC, NN, CC, 0, TL, TL);

  // final BN + LIF -> d_out fp32
  bn_spike_k<1><<<CC, 256, 0, stream>>>(outpre, dout, proj_gamma, proj_beta);
}

// Round 3
// 503.004 us; speedup vs baseline: 4.1464x; 1.0669x over previous
//
#include <hip/hip_runtime.h>
#include <cstddef>

// SSA forward, bf16-MFMA version, round 3: BN split into high-occupancy
// partial-stats + fused apply (old bn_spike_k was 2-blocks/CU latency-bound).
// All 5 GEMMs are NT GEMMs on row-major [rows][K] operands (K contiguous).

#define CC 512
#define BB 32
#define NN 1024

typedef __attribute__((ext_vector_type(8))) short v8s;
typedef __attribute__((ext_vector_type(4))) float v4f;

__device__ __forceinline__ ushort f2bf(float f) {
  unsigned u = __float_as_uint(f);
  unsigned r = (u + 0x7FFFu + ((u >> 16) & 1u)) >> 16;
  return (ushort)r;
}

__device__ __forceinline__ void gload16(const void* g, void* l) {
  __builtin_amdgcn_global_load_lds(
      (const __attribute__((address_space(1))) unsigned int*)g,
      (__attribute__((address_space(3))) unsigned int*)l, 16, 0, 0);
}

// ---------------- batched NT GEMM, 128x128 tile, BK=32, bf16 MFMA ----------------
// C[i][j] = sum_k A[i][k]*B[j][k];  A:[M][K], B:[Ngemm][K], C:[M][Ngemm] row-major.
// EPI: 0 = store bf16(acc); 1 = attn spike; 2 = +bias[row] then bf16.
template <int EPI>
__global__ __launch_bounds__(256) void gemm_nt(const ushort* __restrict__ A,
                                               const ushort* __restrict__ B,
                                               ushort* __restrict__ C,
                                               const float* __restrict__ bias,
                                               int M, int N, int K,
                                               long sA, long sB, long sC) {
  __shared__ __align__(16) short lds[8192];  // A chunks [0,4096), B chunks [4096,8192)
  const int b = blockIdx.z;
  const ushort* Ab = A + (size_t)b * sA;
  const ushort* Bb = B + (size_t)b * sB;
  ushort* Cb = C + (size_t)b * sC;
  const int m0 = blockIdx.y * 128, n0 = blockIdx.x * 128;
  const int tid = threadIdx.x;
  const int wave = tid >> 6, lane = tid & 63;
  const int lrow = lane & 15, lquad = lane >> 4;

  v4f acc[4][4];
#pragma unroll
  for (int i = 0; i < 4; i++)
#pragma unroll
    for (int j = 0; j < 4; j++) acc[i][j] = (v4f)0.f;

  // Staging: 8 A-chunks + 8 B-chunks per K-step, each 16 rows x 32 k in exact
  // MFMA fragment order (lane L: row lrow, k = lquad*8..+7 -> LDS byte L*16).
  const int i0 = 2 * wave;
  const ushort* ga0 = Ab + (size_t)(m0 + 16 * i0 + lrow) * K + lquad * 8;
  const ushort* ga1 = ga0 + (size_t)16 * K;
  const ushort* gb0 = Bb + (size_t)(n0 + 16 * i0 + lrow) * K + lquad * 8;
  const ushort* gb1 = gb0 + (size_t)16 * K;
  short* la0 = lds + i0 * 512;
  short* la1 = la0 + 512;
  short* lb0 = lds + 4096 + i0 * 512;
  short* lb1 = lb0 + 512;
  const int wr = wave >> 1, wc = wave & 1;  // wave quadrant of the 128x128 tile
  const short* ra = lds + (4 * wr) * 512 + lane * 8;
  const short* rb = lds + 4096 + (4 * wc) * 512 + lane * 8;

  for (int k0 = 0; k0 < K; k0 += 32) {
    gload16(ga0, la0);
    gload16(ga1, la1);
    gload16(gb0, lb0);
    gload16(gb1, lb1);
    ga0 += 32; ga1 += 32; gb0 += 32; gb1 += 32;
    __syncthreads();
    v8s af[4], bf[4];
#pragma unroll
    for (int i = 0; i < 4; i++) af[i] = *(const v8s*)(ra + i * 512);
#pragma unroll
    for (int j = 0; j < 4; j++) bf[j] = *(const v8s*)(rb + j * 512);
#pragma unroll
    for (int i = 0; i < 4; i++)
#pragma unroll
      for (int j = 0; j < 4; j++)
        acc[i][j] = __builtin_amdgcn_mfma_f32_16x16x32_bf16(af[i], bf[j], acc[i][j], 0, 0, 0);
    __syncthreads();
  }

  // Epilogue. C/D layout: col = lane&15, row = lquad*4 + reg.
#pragma unroll
  for (int mi = 0; mi < 4; mi++) {
    const int row0 = m0 + 64 * wr + 16 * mi + lquad * 4;
#pragma unroll
    for (int ni = 0; ni < 4; ni++) {
      const int col = n0 + 64 * wc + 16 * ni + lrow;
      ushort* cp = Cb + (size_t)row0 * N + col;
#pragma unroll
      for (int r = 0; r < 4; r++) {
        float v = acc[mi][ni][r];
        ushort o;
        if (EPI == 1) {
          float u = (v * 0.125f) / 1.1f - 0.5f;  // lif(attn*SCALE, 0.5)
          o = (u >= 0.f) ? (ushort)0x3F80 : (ushort)0;
        } else {
          if (EPI == 2) v += bias[row0 + r];
          o = f2bf(v);
        }
        cp[(size_t)r * N] = o;
      }
    }
  }
}

// -------- BN partial stats: grid (8 parts, C channels), [B,C,N] bf16 input -------
// Block (part,c) reduces batches [4*part, 4*part+4) of channel c -> float2 partial.
__global__ __launch_bounds__(256) void stats_part_k(const ushort* __restrict__ in,
                                                    float* __restrict__ P) {
  const int part = blockIdx.x, c = blockIdx.y;
  const int tid = threadIdx.x;
  const int bi = part * 4 + (tid >> 6);  // one batch per wave
  const int lane = tid & 63;
  const ushort* p = in + (size_t)bi * CC * NN + (size_t)c * NN + lane * 16;
  float s = 0.f, s2 = 0.f;
  // each lane: 16 contiguous bf16 (two uint4 loads); wave covers the 1024 elems
  const uint4 u0 = *(const uint4*)p;
  const uint4 u1 = *(const uint4*)(p + 8);
  const unsigned w8[8] = {u0.x, u0.y, u0.z, u0.w, u1.x, u1.y, u1.z, u1.w};
#pragma unroll
  for (int t = 0; t < 8; t++) {
    float f0 = __uint_as_float(w8[t] << 16);
    float f1 = __uint_as_float(w8[t] & 0xFFFF0000u);
    s += f0 + f1;
    s2 += f0 * f0 + f1 * f1;
  }
#pragma unroll
  for (int off = 32; off > 0; off >>= 1) {
    s += __shfl_down(s, off, 64);
    s2 += __shfl_down(s2, off, 64);
  }
  __shared__ float rs[4], rq[4];
  const int w = tid >> 6;
  if (lane == 0) { rs[w] = s; rq[w] = s2; }
  __syncthreads();
  if (tid == 0) {
    float2 o = make_float2(rs[0] + rs[1] + rs[2] + rs[3],
                           rq[0] + rq[1] + rq[2] + rq[3]);
    *(float2*)(P + (size_t)(c * 8 + part) * 2) = o;
  }
}

// -------- BN apply + LIF spike, grid 8192 x 256, 8 elems/thread ------------------
// FOUT: 0 -> bf16 {0,1}, 1 -> fp32 {0,1} (final output).
template <int FOUT>
__global__ __launch_bounds__(256) void apply_spike_k(const ushort* __restrict__ in,
                                                     void* __restrict__ outp,
                                                     const float* __restrict__ P,
                                                     const float* __restrict__ gamma,
                                                     const float* __restrict__ beta) {
  const size_t idx = ((size_t)blockIdx.x * 256 + threadIdx.x) * 8;
  const int c = (int)((idx >> 10) & (CC - 1));
  // reduce the 8 partials (P is 32 KB -> L2-resident)
  const float* pc = P + (size_t)c * 16;
  float4 a = *(const float4*)pc;
  float4 b = *(const float4*)(pc + 4);
  float4 cc4 = *(const float4*)(pc + 8);
  float4 d = *(const float4*)(pc + 12);
  float S = a.x + a.z + b.x + b.z + cc4.x + cc4.z + d.x + d.z;
  float Q = a.y + a.w + b.y + b.w + cc4.y + cc4.w + d.y + d.w;
  const float mean = S * (1.f / 32768.f);
  const float var = fmaxf(Q * (1.f / 32768.f) - mean * mean, 0.f);
  const float rinv = 1.f / sqrtf(var + 1e-5f);
  const float g = gamma[c], bt = beta[c];

  const uint4 u = *(const uint4*)(in + idx);
  const unsigned w4[4] = {u.x, u.y, u.z, u.w};
  float f[8];
#pragma unroll
  for (int t = 0; t < 4; t++) {
    f[2 * t]     = __uint_as_float(w4[t] << 16);
    f[2 * t + 1] = __uint_as_float(w4[t] & 0xFFFF0000u);
  }
  if (FOUT) {
    float of[8];
#pragma unroll
    for (int t = 0; t < 8; t++) {
      float val = g * (f[t] - mean) * rinv + bt;
      of[t] = (val / 1.1f - 1.0f >= 0.f) ? 1.f : 0.f;
    }
    float* op = (float*)outp + idx;
    *(float4*)op = make_float4(of[0], of[1], of[2], of[3]);
    *(float4*)(op + 4) = make_float4(of[4], of[5], of[6], of[7]);
  } else {
    unsigned o[4];
#pragma unroll
    for (int t = 0; t < 4; t++) {
      float v0 = g * (f[2 * t] - mean) * rinv + bt;
      float v1 = g * (f[2 * t + 1] - mean) * rinv + bt;
      unsigned lo = (v0 / 1.1f - 1.0f >= 0.f) ? 0x3F80u : 0u;
      unsigned hi = (v1 / 1.1f - 1.0f >= 0.f) ? 0x3F80u : 0u;
      o[t] = lo | (hi << 16);
    }
    *(uint4*)((ushort*)outp + idx) = make_uint4(o[0], o[1], o[2], o[3]);
  }
}

// ---------------- tiled transpose [B,R,Ncol] -> [B,Ncol,R], out bf16 ------------
template <int FIN>  // 1: fp32 in, 0: bf16 in
__global__ __launch_bounds__(256) void transpose_k(const void* __restrict__ inp,
                                                   ushort* __restrict__ out,
                                                   int R, int Ncol) {
  __shared__ ushort tile[32][33];
  const int b = blockIdx.z;
  const int c0 = blockIdx.x * 32, r0 = blockIdx.y * 32;
  const int tx = threadIdx.x & 31, ty = threadIdx.x >> 5;
  const size_t base = (size_t)b * R * Ncol;
#pragma unroll
  for (int i = 0; i < 32; i += 8) {
    const size_t idx = base + (size_t)(r0 + ty + i) * Ncol + c0 + tx;
    ushort hv;
    if (FIN) hv = f2bf(((const float*)inp)[idx]);
    else hv = ((const ushort*)inp)[idx];
    tile[ty + i][tx] = hv;
  }
  __syncthreads();
#pragma unroll
  for (int i = 0; i < 32; i += 8) {
    out[base + (size_t)(c0 + ty + i) * R + r0 + tx] = tile[tx][ty + i];
  }
}

// ---------------- fp32 -> bf16 weight conversion (4 matrices) -------------------
__global__ __launch_bounds__(256) void wcvt_k(const float* __restrict__ w0, const float* __restrict__ w1,
                                              const float* __restrict__ w2, const float* __restrict__ w3,
                                              ushort* __restrict__ o0, ushort* __restrict__ o1,
                                              ushort* __restrict__ o2, ushort* __restrict__ o3) {
  const float* src;
  ushort* dst;
  switch (blockIdx.y) {
    case 0: src = w0; dst = o0; break;
    case 1: src = w1; dst = o1; break;
    case 2: src = w2; dst = o2; break;
    default: src = w3; dst = o3; break;
  }
  const int i = (blockIdx.x * 256 + threadIdx.x) * 4;
  float4 v = *(const float4*)(src + i);
  ushort4 o;
  o.x = f2bf(v.x); o.y = f2bf(v.y); o.z = f2bf(v.z); o.w = f2bf(v.w);
  *(ushort4*)(dst + i) = o;
}

extern "C" void kernel_launch(void* const* d_in, const int* in_sizes, int n_in,
                              void* d_out, int out_size, void* d_ws, size_t ws_size,
                              hipStream_t stream) {
  const float* x          = (const float*)d_in[0];
  const float* q_w        = (const float*)d_in[1];
  const float* q_gamma    = (const float*)d_in[2];
  const float* q_beta     = (const float*)d_in[3];
  const float* k_w        = (const float*)d_in[4];
  const float* k_gamma    = (const float*)d_in[5];
  const float* k_beta     = (const float*)d_in[6];
  const float* v_w        = (const float*)d_in[7];
  const float* v_gamma    = (const float*)d_in[8];
  const float* v_beta     = (const float*)d_in[9];
  const float* proj_w     = (const float*)d_in[10];
  const float* proj_gamma = (const float*)d_in[11];
  const float* proj_beta  = (const float*)d_in[12];
  const float* proj_b     = (const float*)d_in[13];

  ushort* ws = (ushort*)d_ws;
  const size_t T = (size_t)BB * CC * NN;   // 16,777,216 elems
  ushort* xT    = ws;                      // [B,N,C] bf16; reused as attnT
  ushort* qpre  = ws + T;                  // [B,C,N]; reused as outpre
  ushort* kpre  = ws + 2 * T;
  ushort* vpre  = ws + 3 * T;
  ushort* qTs   = ws + 4 * T;              // [B,N,C] q spikes
  ushort* kvT   = ws + 5 * T;              // [B,C,C] (=[d][c])
  ushort* wqb   = kvT + (size_t)BB * CC * CC;
  ushort* wkb   = wqb + CC * CC;
  ushort* wvb   = wkb + CC * CC;
  ushort* wpb   = wvb + CC * CC;
  float* P      = (float*)(wpb + CC * CC); // BN partials: 512*8*2 floats (32 KB)
  ushort* attnT = xT;
  ushort* outpre = qpre;
  float* dout = (float*)d_out;

  const long TL = (long)CC * NN;      // per-batch [C][N] / [N][C] stride
  const long KVL = (long)CC * CC;

  // x [B,C,N] fp32 -> xT [B,N,C] bf16
  transpose_k<1><<<dim3(NN / 32, CC / 32, BB), 256, 0, stream>>>(x, xT, CC, NN);
  wcvt_k<<<dim3(CC * CC / 1024, 4), 256, 0, stream>>>(q_w, k_w, v_w, proj_w, wqb, wkb, wvb, wpb);

  // q/k/v convs: [o][n] = W * xT^T.  grid (N/128, M/128, B)
  dim3 gconv(NN / 128, CC / 128, BB);
  dim3 gstat(8, CC);
  gemm_nt<0><<<gconv, 256, 0, stream>>>(wqb, xT, qpre, nullptr, CC, NN, CC, 0, TL, TL);
  gemm_nt<0><<<gconv, 256, 0, stream>>>(wkb, xT, kpre, nullptr, CC, NN, CC, 0, TL, TL);
  gemm_nt<0><<<gconv, 256, 0, stream>>>(wvb, xT, vpre, nullptr, CC, NN, CC, 0, TL, TL);

  // q: stats -> apply -> transpose to [B,N,C]
  stats_part_k<<<gstat, 256, 0, stream>>>(qpre, P);
  apply_spike_k<0><<<8192, 256, 0, stream>>>(qpre, qpre, P, q_gamma, q_beta);
  transpose_k<0><<<dim3(NN / 32, CC / 32, BB), 256, 0, stream>>>(qpre, qTs, CC, NN);
  // k, v: stats -> apply (in place)
  stats_part_k<<<gstat, 256, 0, stream>>>(kpre, P);
  apply_spike_k<0><<<8192, 256, 0, stream>>>(kpre, kpre, P, k_gamma, k_beta);
  stats_part_k<<<gstat, 256, 0, stream>>>(vpre, P);
  apply_spike_k<0><<<8192, 256, 0, stream>>>(vpre, vpre, P, v_gamma, v_beta);

  // kvT[d][c] = sum_n v[d][n] k[c][n]
  gemm_nt<0><<<dim3(CC / 128, CC / 128, BB), 256, 0, stream>>>(vpre, kpre, kvT, nullptr, CC, CC, NN, TL, TL, KVL);
  // attnT[n][d] = spike( sum_c qT[n][c] kvT[d][c] * 0.125, vth=0.5 )
  gemm_nt<1><<<dim3(CC / 128, NN / 128, BB), 256, 0, stream>>>(qTs, kvT, attnT, nullptr, NN, CC, CC, TL, KVL, TL);
  // proj: out[o][n] = Wp * attnT^T + bias
  gemm_nt<2><<<gconv, 256, 0, stream>>>(wpb, attnT, outpre, proj_b, CC, NN, CC, 0, TL, TL);

  // final BN + LIF -> d_out fp32
  stats_part_k<<<gstat, 256, 0, stream>>>(outpre, P);
  apply_spike_k<1><<<8192, 256, 0, stream>>>(outpre, dout, P, proj_gamma, proj_beta);
}

// Round 4
// 452.160 us; speedup vs baseline: 4.6127x; 1.1124x over previous
//
#include <hip/hip_runtime.h>
#include <cstddef>

// SSA forward, bf16-MFMA, round 4:
//  - q/k/v convs merged into one M=1536 GEMM (3x blocks -> occupancy)
//  - BN folded to per-channel affine (a,b) via finalize_k; spike = a*x+b >= 1.1
//  - q's BN-apply fused into the transpose (one less 64 MB pass)

#define CC 512
#define BB 32
#define NN 1024

typedef __attribute__((ext_vector_type(8))) short v8s;
typedef __attribute__((ext_vector_type(4))) float v4f;

__device__ __forceinline__ ushort f2bf(float f) {
  unsigned u = __float_as_uint(f);
  unsigned r = (u + 0x7FFFu + ((u >> 16) & 1u)) >> 16;
  return (ushort)r;
}

__device__ __forceinline__ void gload16(const void* g, void* l) {
  __builtin_amdgcn_global_load_lds(
      (const __attribute__((address_space(1))) unsigned int*)g,
      (__attribute__((address_space(3))) unsigned int*)l, 16, 0, 0);
}

// ---------------- batched NT GEMM, 128x128 tile, BK=32, bf16 MFMA ----------------
// C[i][j] = sum_k A[i][k]*B[j][k];  A:[M][K], B:[Ngemm][K], C:[M][Ngemm] row-major.
// EPI: 0 = store bf16(acc); 1 = attn spike; 2 = +bias[row] then bf16.
template <int EPI>
__global__ __launch_bounds__(256) void gemm_nt(const ushort* __restrict__ A,
                                               const ushort* __restrict__ B,
                                               ushort* __restrict__ C,
                                               const float* __restrict__ bias,
                                               int M, int N, int K,
                                               long sA, long sB, long sC) {
  __shared__ __align__(16) short lds[8192];  // A chunks [0,4096), B chunks [4096,8192)
  const int b = blockIdx.z;
  const ushort* Ab = A + (size_t)b * sA;
  const ushort* Bb = B + (size_t)b * sB;
  ushort* Cb = C + (size_t)b * sC;
  const int m0 = blockIdx.y * 128, n0 = blockIdx.x * 128;
  const int tid = threadIdx.x;
  const int wave = tid >> 6, lane = tid & 63;
  const int lrow = lane & 15, lquad = lane >> 4;

  v4f acc[4][4];
#pragma unroll
  for (int i = 0; i < 4; i++)
#pragma unroll
    for (int j = 0; j < 4; j++) acc[i][j] = (v4f)0.f;

  // Staging: 8 A-chunks + 8 B-chunks per K-step, each 16 rows x 32 k in exact
  // MFMA fragment order (lane L: row lrow, k = lquad*8..+7 -> LDS byte L*16).
  const int i0 = 2 * wave;
  const ushort* ga0 = Ab + (size_t)(m0 + 16 * i0 + lrow) * K + lquad * 8;
  const ushort* ga1 = ga0 + (size_t)16 * K;
  const ushort* gb0 = Bb + (size_t)(n0 + 16 * i0 + lrow) * K + lquad * 8;
  const ushort* gb1 = gb0 + (size_t)16 * K;
  short* la0 = lds + i0 * 512;
  short* la1 = la0 + 512;
  short* lb0 = lds + 4096 + i0 * 512;
  short* lb1 = lb0 + 512;
  const int wr = wave >> 1, wc = wave & 1;  // wave quadrant of the 128x128 tile
  const short* ra = lds + (4 * wr) * 512 + lane * 8;
  const short* rb = lds + 4096 + (4 * wc) * 512 + lane * 8;

  for (int k0 = 0; k0 < K; k0 += 32) {
    gload16(ga0, la0);
    gload16(ga1, la1);
    gload16(gb0, lb0);
    gload16(gb1, lb1);
    ga0 += 32; ga1 += 32; gb0 += 32; gb1 += 32;
    __syncthreads();
    v8s af[4], bf[4];
#pragma unroll
    for (int i = 0; i < 4; i++) af[i] = *(const v8s*)(ra + i * 512);
#pragma unroll
    for (int j = 0; j < 4; j++) bf[j] = *(const v8s*)(rb + j * 512);
#pragma unroll
    for (int i = 0; i < 4; i++)
#pragma unroll
      for (int j = 0; j < 4; j++)
        acc[i][j] = __builtin_amdgcn_mfma_f32_16x16x32_bf16(af[i], bf[j], acc[i][j], 0, 0, 0);
    __syncthreads();
  }

  // Epilogue. C/D layout: col = lane&15, row = lquad*4 + reg.
#pragma unroll
  for (int mi = 0; mi < 4; mi++) {
    const int row0 = m0 + 64 * wr + 16 * mi + lquad * 4;
#pragma unroll
    for (int ni = 0; ni < 4; ni++) {
      const int col = n0 + 64 * wc + 16 * ni + lrow;
      ushort* cp = Cb + (size_t)row0 * N + col;
#pragma unroll
      for (int r = 0; r < 4; r++) {
        float v = acc[mi][ni][r];
        ushort o;
        if (EPI == 1) {
          float u = (v * 0.125f) / 1.1f - 0.5f;  // lif(attn*SCALE, 0.5)
          o = (u >= 0.f) ? (ushort)0x3F80 : (ushort)0;
        } else {
          if (EPI == 2) v += bias[row0 + r];
          o = f2bf(v);
        }
        cp[(size_t)r * N] = o;
      }
    }
  }
}

// -------- BN partial stats: grid (8 parts, CH channels) ---------------------------
// Rows are length-1024 (n). Row (b, c) at in + b*bstride + c*1024.
// Block (part,c) reduces batches [4*part, 4*part+4) -> P[c][part] = (sum, sumsq).
__global__ __launch_bounds__(256) void stats_part_k(const ushort* __restrict__ in,
                                                    float* __restrict__ P,
                                                    long bstride) {
  const int part = blockIdx.x, c = blockIdx.y;
  const int tid = threadIdx.x;
  const int bi = part * 4 + (tid >> 6);  // one batch per wave
  const int lane = tid & 63;
  const ushort* p = in + (size_t)bi * bstride + (size_t)c * 1024 + lane * 16;
  float s = 0.f, s2 = 0.f;
  const uint4 u0 = *(const uint4*)p;
  const uint4 u1 = *(const uint4*)(p + 8);
  const unsigned w8[8] = {u0.x, u0.y, u0.z, u0.w, u1.x, u1.y, u1.z, u1.w};
#pragma unroll
  for (int t = 0; t < 8; t++) {
    float f0 = __uint_as_float(w8[t] << 16);
    float f1 = __uint_as_float(w8[t] & 0xFFFF0000u);
    s += f0 + f1;
    s2 += f0 * f0 + f1 * f1;
  }
#pragma unroll
  for (int off = 32; off > 0; off >>= 1) {
    s += __shfl_down(s, off, 64);
    s2 += __shfl_down(s2, off, 64);
  }
  __shared__ float rs[4], rq[4];
  const int w = tid >> 6;
  if (lane == 0) { rs[w] = s; rq[w] = s2; }
  __syncthreads();
  if (tid == 0) {
    float2 o = make_float2(rs[0] + rs[1] + rs[2] + rs[3],
                           rq[0] + rq[1] + rq[2] + rq[3]);
    *(float2*)(P + (size_t)(c * 8 + part) * 2) = o;
  }
}

// -------- finalize: P[c][8][2] -> F[c] = (a, b) with spike <=> a*x + b >= 1.1 -----
__global__ __launch_bounds__(256) void finalize_k(const float* __restrict__ P,
                                                  float2* __restrict__ F,
                                                  const float* __restrict__ g0, const float* __restrict__ b0,
                                                  const float* __restrict__ g1, const float* __restrict__ b1,
                                                  const float* __restrict__ g2, const float* __restrict__ b2,
                                                  int nch) {
  const int c = blockIdx.x * 256 + threadIdx.x;
  if (c >= nch) return;
  const float* pc = P + (size_t)c * 16;
  float S = 0.f, Q = 0.f;
#pragma unroll
  for (int t = 0; t < 8; t++) { S += pc[2 * t]; Q += pc[2 * t + 1]; }
  const float mean = S * (1.f / 32768.f);
  const float var = fmaxf(Q * (1.f / 32768.f) - mean * mean, 0.f);
  const float rinv = 1.f / sqrtf(var + 1e-5f);
  const int sec = c >> 9, cl = c & 511;
  const float g = (sec == 0 ? g0 : sec == 1 ? g1 : g2)[cl];
  const float bt = (sec == 0 ? b0 : sec == 1 ? b1 : b2)[cl];
  const float a = g * rinv;
  F[c] = make_float2(a, bt - mean * a);
}

// -------- apply spike in place on k/v sections of qkv [B][1536][1024] -------------
__global__ __launch_bounds__(256) void apply_kv_k(ushort* __restrict__ qkv,
                                                  const float2* __restrict__ F) {
  const size_t t = (size_t)blockIdx.x * 256 + threadIdx.x;  // 4.19M threads
  const int n8 = (int)(t & 127);
  const int cL = (int)((t >> 7) & 1023);
  const int b = (int)(t >> 17);
  const float2 ab = F[512 + cL];
  ushort* p = qkv + (size_t)b * (1536 * 1024) + (size_t)(512 + cL) * 1024 + n8 * 8;
  const uint4 u = *(const uint4*)p;
  const unsigned w4[4] = {u.x, u.y, u.z, u.w};
  unsigned o[4];
#pragma unroll
  for (int i = 0; i < 4; i++) {
    float f0 = __uint_as_float(w4[i] << 16);
    float f1 = __uint_as_float(w4[i] & 0xFFFF0000u);
    unsigned lo = (ab.x * f0 + ab.y >= 1.1f) ? 0x3F80u : 0u;
    unsigned hi = (ab.x * f1 + ab.y >= 1.1f) ? 0x3F80u : 0u;
    o[i] = lo | (hi << 16);
  }
  *(uint4*)p = make_uint4(o[0], o[1], o[2], o[3]);
}

// -------- fused BN-apply + spike + transpose: q section -> qTs [B][N][C] ----------
__global__ __launch_bounds__(256) void apply_qT_k(const ushort* __restrict__ qkv,
                                                  ushort* __restrict__ qTs,
                                                  const float2* __restrict__ F) {
  __shared__ ushort tile[32][33];
  const int b = blockIdx.z;
  const int n0 = blockIdx.x * 32, c0 = blockIdx.y * 32;
  const int tx = threadIdx.x & 31, ty = threadIdx.x >> 5;
  const ushort* in = qkv + (size_t)b * (1536 * 1024);
#pragma unroll
  for (int i = 0; i < 32; i += 8) {
    const int c = c0 + ty + i;
    const float2 ab = F[c];
    float f = __uint_as_float((unsigned)in[(size_t)c * 1024 + n0 + tx] << 16);
    tile[ty + i][tx] = (ab.x * f + ab.y >= 1.1f) ? (ushort)0x3F80 : (ushort)0;
  }
  __syncthreads();
  ushort* out = qTs + (size_t)b * (NN * CC);
#pragma unroll
  for (int i = 0; i < 32; i += 8) {
    out[(size_t)(n0 + ty + i) * CC + c0 + tx] = tile[tx][ty + i];
  }
}

// -------- final BN apply + spike -> fp32 output -----------------------------------
__global__ __launch_bounds__(256) void apply_final_k(const ushort* __restrict__ in,
                                                     float* __restrict__ outp,
                                                     const float2* __restrict__ F) {
  const size_t idx = ((size_t)blockIdx.x * 256 + threadIdx.x) * 8;
  const int c = (int)((idx >> 10) & (CC - 1));
  const float2 ab = F[c];
  const uint4 u = *(const uint4*)(in + idx);
  const unsigned w4[4] = {u.x, u.y, u.z, u.w};
  float of[8];
#pragma unroll
  for (int i = 0; i < 4; i++) {
    float f0 = __uint_as_float(w4[i] << 16);
    float f1 = __uint_as_float(w4[i] & 0xFFFF0000u);
    of[2 * i]     = (ab.x * f0 + ab.y >= 1.1f) ? 1.f : 0.f;
    of[2 * i + 1] = (ab.x * f1 + ab.y >= 1.1f) ? 1.f : 0.f;
  }
  float* op = outp + idx;
  *(float4*)op = make_float4(of[0], of[1], of[2], of[3]);
  *(float4*)(op + 4) = make_float4(of[4], of[5], of[6], of[7]);
}

// ---------------- tiled transpose [B,R,Ncol] fp32 -> [B,Ncol,R] bf16 --------------
__global__ __launch_bounds__(256) void transpose_f32_k(const float* __restrict__ inp,
                                                       ushort* __restrict__ out,
                                                       int R, int Ncol) {
  __shared__ ushort tile[32][33];
  const int b = blockIdx.z;
  const int c0 = blockIdx.x * 32, r0 = blockIdx.y * 32;
  const int tx = threadIdx.x & 31, ty = threadIdx.x >> 5;
  const size_t base = (size_t)b * R * Ncol;
#pragma unroll
  for (int i = 0; i < 32; i += 8) {
    tile[ty + i][tx] = f2bf(inp[base + (size_t)(r0 + ty + i) * Ncol + c0 + tx]);
  }
  __syncthreads();
#pragma unroll
  for (int i = 0; i < 32; i += 8) {
    out[base + (size_t)(c0 + ty + i) * R + r0 + tx] = tile[tx][ty + i];
  }
}

// ---------------- fp32 -> bf16 weight conversion (4 matrices) ---------------------
__global__ __launch_bounds__(256) void wcvt_k(const float* __restrict__ w0, const float* __restrict__ w1,
                                              const float* __restrict__ w2, const float* __restrict__ w3,
                                              ushort* __restrict__ o0, ushort* __restrict__ o1,
                                              ushort* __restrict__ o2, ushort* __restrict__ o3) {
  const float* src;
  ushort* dst;
  switch (blockIdx.y) {
    case 0: src = w0; dst = o0; break;
    case 1: src = w1; dst = o1; break;
    case 2: src = w2; dst = o2; break;
    default: src = w3; dst = o3; break;
  }
  const int i = (blockIdx.x * 256 + threadIdx.x) * 4;
  float4 v = *(const float4*)(src + i);
  ushort4 o;
  o.x = f2bf(v.x); o.y = f2bf(v.y); o.z = f2bf(v.z); o.w = f2bf(v.w);
  *(ushort4*)(dst + i) = o;
}

extern "C" void kernel_launch(void* const* d_in, const int* in_sizes, int n_in,
                              void* d_out, int out_size, void* d_ws, size_t ws_size,
                              hipStream_t stream) {
  const float* x          = (const float*)d_in[0];
  const float* q_w        = (const float*)d_in[1];
  const float* q_gamma    = (const float*)d_in[2];
  const float* q_beta     = (const float*)d_in[3];
  const float* k_w        = (const float*)d_in[4];
  const float* k_gamma    = (const float*)d_in[5];
  const float* k_beta     = (const float*)d_in[6];
  const float* v_w        = (const float*)d_in[7];
  const float* v_gamma    = (const float*)d_in[8];
  const float* v_beta     = (const float*)d_in[9];
  const float* proj_w     = (const float*)d_in[10];
  const float* proj_gamma = (const float*)d_in[11];
  const float* proj_beta  = (const float*)d_in[12];
  const float* proj_b     = (const float*)d_in[13];

  ushort* ws = (ushort*)d_ws;
  const size_t T = (size_t)BB * CC * NN;   // 16,777,216 elems
  ushort* xT    = ws;                      // [B,N,C] bf16; reused as attnT
  ushort* qkv   = ws + T;                  // [B,1536,1024]; q section reused as outpre
  ushort* qTs   = ws + 4 * T;              // [B,N,C] q spikes
  ushort* kvT   = ws + 5 * T;              // [B,C,C]
  ushort* wqkv  = kvT + (size_t)BB * CC * CC;  // stacked q|k|v weights
  ushort* wpb   = wqkv + 3 * CC * CC;
  float*  P     = (float*)(wpb + CC * CC);     // partials: 1536*16 floats
  float2* F     = (float2*)(P + 1536 * 16);    // per-channel affine
  ushort* attnT = xT;
  ushort* outpre = qkv;                        // [B,C,N], stride 512*1024
  float* dout = (float*)d_out;

  const long TL   = (long)CC * NN;       // 524288
  const long QKVL = (long)3 * CC * NN;   // 1572864
  const long KVL  = (long)CC * CC;
  const long OUTL = (long)CC * NN;

  // x [B,C,N] fp32 -> xT [B,N,C] bf16
  transpose_f32_k<<<dim3(NN / 32, CC / 32, BB), 256, 0, stream>>>(x, xT, CC, NN);
  wcvt_k<<<dim3(CC * CC / 1024, 4), 256, 0, stream>>>(
      q_w, k_w, v_w, proj_w, wqkv, wqkv + CC * CC, wqkv + 2 * CC * CC, wpb);

  // merged q/k/v conv: [1536][1024] per batch = Wqkv * xT^T
  gemm_nt<0><<<dim3(NN / 128, 1536 / 128, BB), 256, 0, stream>>>(
      wqkv, xT, qkv, nullptr, 1536, NN, CC, 0, TL, QKVL);

  // BN stats over all 1536 channels, fold to affine
  stats_part_k<<<dim3(8, 1536), 256, 0, stream>>>(qkv, P, QKVL);
  finalize_k<<<6, 256, 0, stream>>>(P, F, q_gamma, q_beta, k_gamma, k_beta, v_gamma, v_beta, 1536);

  // q: fused apply+transpose -> qTs; k,v: apply in place
  apply_qT_k<<<dim3(NN / 32, CC / 32, BB), 256, 0, stream>>>(qkv, qTs, F);
  apply_kv_k<<<16384, 256, 0, stream>>>(qkv, F);

  // kvT[d][c] = sum_n v[d][n] k[c][n]
  gemm_nt<0><<<dim3(CC / 128, CC / 128, BB), 256, 0, stream>>>(
      qkv + (size_t)2 * CC * NN, qkv + (size_t)CC * NN, kvT, nullptr, CC, CC, NN, QKVL, QKVL, KVL);
  // attnT[n][d] = spike( sum_c qT[n][c] kvT[d][c] * 0.125, vth=0.5 )
  gemm_nt<1><<<dim3(CC / 128, NN / 128, BB), 256, 0, stream>>>(
      qTs, kvT, attnT, nullptr, NN, CC, CC, TL, KVL, TL);
  // proj: out[o][n] = Wp * attnT^T + bias   (overwrites q/k/v regions, now dead)
  gemm_nt<2><<<dim3(NN / 128, CC / 128, BB), 256, 0, stream>>>(
      wpb, attnT, outpre, proj_b, CC, NN, CC, 0, TL, OUTL);

  // final BN + LIF -> d_out fp32
  stats_part_k<<<dim3(8, CC), 256, 0, stream>>>(outpre, P, OUTL);
  finalize_k<<<2, 256, 0, stream>>>(P, F, proj_gamma, proj_beta, proj_gamma, proj_beta,
                                    proj_gamma, proj_beta, CC);
  apply_final_k<<<8192, 256, 0, stream>>>(outpre, dout, F);
}